// Round 6
// baseline (10173.053 us; speedup 1.0000x reference)
//
#include <hip/hip_runtime.h>

// ---------------------------------------------------------------------------
// Naive GEMM: one thread per (m,n). C = act(scale*A@op(B) + bias)
// A [M,K] row-major lda. TRANSB=0: B[k*ldb+n]; TRANSB=1: B[n*ldb+k].
// ---------------------------------------------------------------------------
template<int TRANSB, int RELU, int ACCUM, int HAS_BIAS>
__global__ __launch_bounds__(256) void ngemm(
    const float* __restrict__ A, long lda, long aoff,
    const float* __restrict__ B, long ldb, long boff,
    float* __restrict__ C, long ldc, long coff,
    const float* __restrict__ bias, long biasoff,
    int M, int N, int K, float scale)
{
    long t = (long)blockIdx.x * 256 + threadIdx.x;
    if (t >= (long)M * N) return;
    int m = (int)(t / N), n = (int)(t % N);
    int bz = blockIdx.z;
    const float* a = A + (long)bz * aoff + (long)m * lda;
    const float* b = B + (long)bz * boff;
    float acc = 0.f;
    if (TRANSB) {
        b += (long)n * ldb;
        for (int k = 0; k < K; k++) acc += a[k] * b[k];
    } else {
        b += n;
        for (int k = 0; k < K; k++) acc += a[k] * b[(long)k * ldb];
    }
    float v = acc * scale;
    if (HAS_BIAS) v += bias[(long)bz * biasoff + n];
    if (RELU) v = fmaxf(v, 0.f);
    long ci = (long)bz * coff + (long)m * ldc + n;
    if (ACCUM) C[ci] += v; else C[ci] = v;
}

// slots = mu + exp(logsigma) * noise
__global__ __launch_bounds__(256) void init_slots_k(const float* __restrict__ noise,
                                                    const float* __restrict__ mu,
                                                    const float* __restrict__ ls,
                                                    float* __restrict__ slots)
{
    int idx = blockIdx.x * 256 + threadIdx.x;  // < 524288
    int d = idx & 2047;
    slots[idx] = mu[d] + expf(ls[d]) * noise[idx];
}

// LN over 256, one THREAD per row
__global__ __launch_bounds__(256) void ln_in_k(const float* __restrict__ in,
                                               const float* __restrict__ g,
                                               const float* __restrict__ b,
                                               float* __restrict__ out)
{
    int row = blockIdx.x * 256 + threadIdx.x;  // < 32768
    long base = (long)row * 256;
    float s = 0.f;
    for (int i = 0; i < 256; i++) s += in[base + i];
    float mean = s * (1.f / 256.f);
    float sq = 0.f;
    for (int i = 0; i < 256; i++) { float d = in[base + i] - mean; sq += d * d; }
    float inv = rsqrtf(sq * (1.f / 256.f) + 1e-5f);
    for (int i = 0; i < 256; i++) out[base + i] = (in[base + i] - mean) * inv * g[i] + b[i];
}

// LN over 2048, one THREAD per row (256 rows)
__global__ __launch_bounds__(256) void ln_slots_k(const float* __restrict__ slots,
                                                  const float* __restrict__ g,
                                                  const float* __restrict__ b,
                                                  float* __restrict__ out)
{
    int row = threadIdx.x;  // 0..255, single block
    long base = (long)row * 2048;
    float s = 0.f;
    for (int i = 0; i < 2048; i++) s += slots[base + i];
    float mean = s * (1.f / 2048.f);
    float sq = 0.f;
    for (int i = 0; i < 2048; i++) { float d = slots[base + i] - mean; sq += d * d; }
    float inv = rsqrtf(sq * (1.f / 2048.f) + 1e-5f);
    for (int i = 0; i < 2048; i++) out[base + i] = (slots[base + i] - mean) * inv * g[i] + b[i];
}

// softmax over n (1024, stride 8) + EPS + renorm; one THREAD per (b,s)
__global__ __launch_bounds__(256) void softmax_k(const float* __restrict__ dots,
                                                 float* __restrict__ attn)
{
    int t = threadIdx.x;  // single block of 256
    int b = t >> 3, s = t & 7;
    long base = (long)b * 8192 + s;
    float mx = -1e30f;
    for (int n = 0; n < 1024; n++) mx = fmaxf(mx, dots[base + n * 8]);
    float sum = 0.f;
    for (int n = 0; n < 1024; n++) sum += expf(dots[base + n * 8] - mx);
    float inv = 1.f / sum;
    float sum2 = 0.f;
    for (int n = 0; n < 1024; n++) sum2 += expf(dots[base + n * 8] - mx) * inv + 1e-8f;
    float inv2 = 1.f / sum2;
    for (int n = 0; n < 1024; n++)
        attn[base + n * 8] = (expf(dots[base + n * 8] - mx) * inv + 1e-8f) * inv2;
}

// u'[b,s,i] = sum_n attn[b,n,s]*x[b,n,i]; one thread per (b,s,i)
__global__ __launch_bounds__(256) void uprime_k(const float* __restrict__ attn,
                                                const float* __restrict__ x,
                                                float* __restrict__ up)
{
    int t = blockIdx.x * 256 + threadIdx.x;  // < 65536
    int b = t >> 11;
    int rem = t & 2047;
    int s = rem >> 8, i = rem & 255;
    const float* ap = attn + (long)b * 8192 + s;
    const float* xp = x + (long)b * 262144 + i;
    float acc = 0.f;
    for (int n = 0; n < 1024; n++) acc += ap[n * 8] * xp[n * 256];
    up[(long)b * 2048 + s * 256 + i] = acc;
}

// GRU gates elementwise
__global__ __launch_bounds__(256) void gru_k(const float* __restrict__ gi,
                                             const float* __restrict__ gh,
                                             const float* __restrict__ bih,
                                             const float* __restrict__ bhh,
                                             float* __restrict__ slots)
{
    int idx = blockIdx.x * 256 + threadIdx.x;  // < 524288
    int r = idx >> 11, c = idx & 2047;
    int nb = c >> 7, j = c & 127;
    long gbase = (long)r * 6144 + nb * 384 + j;
    int bbase = nb * 384 + j;
    float ir  = gi[gbase]       + bih[bbase];
    float iz  = gi[gbase + 128] + bih[bbase + 128];
    float in_ = gi[gbase + 256] + bih[bbase + 256];
    float hr  = gh[gbase]       + bhh[bbase];
    float hz  = gh[gbase + 128] + bhh[bbase + 128];
    float hn  = gh[gbase + 256] + bhh[bbase + 256];
    float rg = 1.f / (1.f + expf(-(ir + hr)));
    float zg = 1.f / (1.f + expf(-(iz + hz)));
    float nn = tanhf(in_ + rg * hn);
    float h = slots[idx];
    slots[idx] = (1.f - zg) * nn + zg * h;
}

// BLN over 128-blocks; one THREAD per block-row
__global__ __launch_bounds__(256) void bln_k(const float* __restrict__ in,
                                             float* __restrict__ out, int nrows)
{
    int row = blockIdx.x * 256 + threadIdx.x;
    if (row >= nrows) return;
    long base = (long)row * 128;
    float s = 0.f;
    for (int i = 0; i < 128; i++) s += in[base + i];
    float mean = s * (1.f / 128.f);
    float sq = 0.f;
    for (int i = 0; i < 128; i++) { float d = in[base + i] - mean; sq += d * d; }
    float inv = rsqrtf(sq * (1.f / 128.f) + 1e-5f);
    for (int i = 0; i < 128; i++) out[base + i] = (in[base + i] - mean) * inv;
}

// bwa stage 1: per (b,t,nb) mean + inv(scaled by BD^-0.5) of slot block
__global__ __launch_bounds__(256) void bwa_stat_k(const float* __restrict__ slots,
                                                  float* __restrict__ stat)
{
    int t = blockIdx.x * 256 + threadIdx.x;  // < 4096 = (b*8+t8)*16+nb
    int nb = t & 15, row = t >> 4;
    long base = (long)row * 2048 + nb * 128;
    float s = 0.f;
    for (int i = 0; i < 128; i++) s += slots[base + i];
    float mean = s * (1.f / 128.f);
    float sq = 0.f;
    for (int i = 0; i < 128; i++) { float d = slots[base + i] - mean; sq += d * d; }
    float inv = rsqrtf(sq * (1.f / 128.f) + 1e-5f) * 0.08838834764831845f;
    stat[t * 2] = mean;
    stat[t * 2 + 1] = inv;
}

// bwa stage 2: scores[(b,t8,nb),p] = qn . mem_p
__global__ __launch_bounds__(256) void bwa_score_k(const float* __restrict__ slots,
                                                   const float* __restrict__ mem,
                                                   const float* __restrict__ stat,
                                                   float* __restrict__ sc)
{
    int t = blockIdx.x * 256 + threadIdx.x;  // < 262144
    int p = t & 63;
    int grp = t >> 6;            // (b*8+t8)*16+nb
    int nb = grp & 15, row = grp >> 4;
    long sbase = (long)row * 2048 + nb * 128;
    long mbase = (long)(p * 16 + nb) * 128;
    float mean = stat[grp * 2], inv = stat[grp * 2 + 1];
    float acc = 0.f;
    for (int j = 0; j < 128; j++) acc += (slots[sbase + j] - mean) * inv * mem[mbase + j];
    sc[t] = acc;
}

// bwa stage 3: softmax over p (64); one THREAD per group
__global__ __launch_bounds__(256) void bwa_soft_k(float* __restrict__ sc)
{
    int grp = blockIdx.x * 256 + threadIdx.x;  // < 4096
    long base = (long)grp * 64;
    float mx = -1e30f;
    for (int p = 0; p < 64; p++) mx = fmaxf(mx, sc[base + p]);
    float sum = 0.f;
    for (int p = 0; p < 64; p++) sum += expf(sc[base + p] - mx);
    float inv = 1.f / sum;
    for (int p = 0; p < 64; p++) sc[base + p] = expf(sc[base + p] - mx) * inv;
}

// bwa stage 4: slots[(b,t8),nb*128+j] = sum_p a_p * mem[p,nb,j]
__global__ __launch_bounds__(256) void bwa_out_k(const float* __restrict__ sc,
                                                 const float* __restrict__ mem,
                                                 float* __restrict__ slots)
{
    int t = blockIdx.x * 256 + threadIdx.x;  // < 524288
    int j = t & 127;
    int grp = t >> 7;            // (b*8+t8)*16+nb
    int nb = grp & 15, row = grp >> 4;
    const float* a = sc + (long)grp * 64;
    float acc = 0.f;
    for (int p = 0; p < 64; p++) acc += a[p] * mem[(long)(p * 16 + nb) * 128 + j];
    slots[(long)row * 2048 + nb * 128 + j] = acc;
}

// OUTPUT IS FLOAT32: reference returns f32 arrays; harness reads d_out as float*
__global__ __launch_bounds__(256) void out_k(const float* __restrict__ slots,
                                             const float* __restrict__ attn,
                                             float* __restrict__ out)
{
    int idx = blockIdx.x * 256 + threadIdx.x;  // < 786432
    out[idx] = (idx < 524288) ? slots[idx] : attn[idx - 524288];
}

// ===========================================================================
extern "C" void kernel_launch(void* const* d_in, const int* in_sizes, int n_in,
                              void* d_out, int out_size, void* d_ws, size_t ws_size,
                              hipStream_t stream)
{
    (void)in_sizes; (void)n_in; (void)out_size; (void)ws_size;
    const float* inputs = (const float*)d_in[0];
    const float* noise  = (const float*)d_in[1];
    const float* smu    = (const float*)d_in[2];
    const float* sls    = (const float*)d_in[3];
    const float* Wq     = (const float*)d_in[4];
    const float* bq     = (const float*)d_in[5];
    const float* Wk     = (const float*)d_in[6];
    /* d_in[7] = bk: zero AND softmax(axis=n)-invariant; dropped */
    const float* Wv     = (const float*)d_in[8];
    const float* bv     = (const float*)d_in[9];
    const float* gWih   = (const float*)d_in[10];
    const float* gWhh   = (const float*)d_in[11];
    const float* gbih   = (const float*)d_in[12];
    const float* gbhh   = (const float*)d_in[13];
    const float* mW1    = (const float*)d_in[14];
    const float* mb1    = (const float*)d_in[15];
    const float* mW2    = (const float*)d_in[16];
    const float* mb2    = (const float*)d_in[17];
    const float* cvec   = (const float*)d_in[18];
    const float* cW1    = (const float*)d_in[19];
    const float* cb1    = (const float*)d_in[20];
    const float* cW2    = (const float*)d_in[21];
    const float* cb2    = (const float*)d_in[22];
    const float* cW3    = (const float*)d_in[23];
    const float* cb3    = (const float*)d_in[24];
    const float* cW4    = (const float*)d_in[25];
    const float* cb4    = (const float*)d_in[26];
    const float* nig    = (const float*)d_in[27];
    const float* nib    = (const float*)d_in[28];
    const float* nsg    = (const float*)d_in[29];
    const float* nsb    = (const float*)d_in[30];

    char* w = (char*)d_ws;
    auto take = [&](size_t bytes) -> char* {
        char* p = w;
        w += (bytes + 255) & ~(size_t)255;
        return p;
    };

    float* slots = (float*)take((size_t)524288 * 4);
    float* xf    = (float*)take((size_t)32768 * 256 * 4);
    float* s_ln  = (float*)take((size_t)256 * 2048 * 4);
    float* qf    = (float*)take((size_t)256 * 2048 * 4);
    float* kqT   = (float*)take((size_t)256 * 256 * 4);
    float* dots  = (float*)take((size_t)32 * 1024 * 8 * 4);
    float* attn  = (float*)take((size_t)32 * 1024 * 8 * 4);
    float* up    = (float*)take((size_t)256 * 256 * 4);
    float* upd   = (float*)take((size_t)256 * 2048 * 4);
    float* gi    = (float*)take((size_t)256 * 6144 * 4);
    float* gh    = (float*)take((size_t)256 * 6144 * 4);
    float* t1    = (float*)take((size_t)256 * 2048 * 4);
    float* t2    = (float*)take((size_t)256 * 2048 * 4);
    float* hA    = (float*)take((size_t)1024 * 512 * 4);
    float* hB    = (float*)take((size_t)1024 * 512 * 4);
    float* h4    = (float*)take((size_t)1024 * 128 * 4);
    float* memf  = (float*)take((size_t)1024 * 128 * 4);
    float* stat  = (float*)take((size_t)4096 * 2 * 4);
    float* bwsc  = (float*)take((size_t)262144 * 4);

    init_slots_k<<<2048, 256, 0, stream>>>(noise, smu, sls, slots);
    ln_in_k<<<128, 256, 0, stream>>>(inputs, nig, nib, xf);

    // --- concept memory (iteration-invariant) -----------------------------
    ngemm<0,1,0,1><<<dim3(2048,1,1), 256, 0, stream>>>(cvec, 128, 0, cW1, 512, 0, hA, 512, 0, cb1, 0, 1024, 512, 128, 1.f);
    ngemm<0,1,0,1><<<dim3(2048,1,1), 256, 0, stream>>>(hA, 512, 0, cW2, 512, 0, hB, 512, 0, cb2, 0, 1024, 512, 512, 1.f);
    ngemm<0,1,0,1><<<dim3(2048,1,1), 256, 0, stream>>>(hB, 512, 0, cW3, 512, 0, hA, 512, 0, cb3, 0, 1024, 512, 512, 1.f);
    ngemm<0,0,0,1><<<dim3(512,1,1),  256, 0, stream>>>(hA, 512, 0, cW4, 128, 0, h4, 128, 0, cb4, 0, 1024, 128, 512, 1.f);
    bln_k<<<4, 256, 0, stream>>>(h4, memf, 1024);

    for (int it = 0; it < 3; ++it) {
        ln_slots_k<<<1, 256, 0, stream>>>(slots, nsg, nsb, s_ln);
        // q = s_ln @ Wq + bq
        ngemm<0,0,0,1><<<dim3(2048,1,1), 256, 0, stream>>>(s_ln, 2048, 0, Wq, 2048, 0, qf, 2048, 0, bq, 0, 256, 2048, 2048, 1.f);
        // kqT[bs,i] = q . Wk[i,:]
        ngemm<1,0,0,0><<<dim3(256,1,1), 256, 0, stream>>>(qf, 2048, 0, Wk, 2048, 0, kqT, 256, 0, nullptr, 0, 256, 256, 2048, 1.f);
        // dots[b,n,s] = scale * x[b,n,:] . kqT[b*8+s,:]
        ngemm<1,0,0,0><<<dim3(32,1,32), 256, 0, stream>>>(xf, 256, 262144, kqT, 256, 2048, dots, 8, 8192, nullptr, 0, 1024, 8, 256, 0.022097086912079608f);
        softmax_k<<<1, 256, 0, stream>>>(dots, attn);
        uprime_k<<<256, 256, 0, stream>>>(attn, xf, up);
        // updates = up @ Wv + bv  (sum_n attn == 1)
        ngemm<0,0,0,1><<<dim3(2048,1,1), 256, 0, stream>>>(up, 256, 0, Wv, 2048, 0, upd, 2048, 0, bv, 0, 256, 2048, 256, 1.f);
        // GRU gates
        ngemm<1,0,0,0><<<dim3(384,1,16), 256, 0, stream>>>(upd, 2048, 128, gWih, 128, 49152, gi, 6144, 384, nullptr, 0, 256, 384, 128, 1.f);
        ngemm<1,0,0,0><<<dim3(384,1,16), 256, 0, stream>>>(slots, 2048, 128, gWhh, 128, 49152, gh, 6144, 384, nullptr, 0, 256, 384, 128, 1.f);
        gru_k<<<2048, 256, 0, stream>>>(gi, gh, gbih, gbhh, slots);
        // residual block-MLP
        bln_k<<<16, 256, 0, stream>>>(slots, t1, 4096);
        ngemm<0,1,0,1><<<dim3(128,1,16), 256, 0, stream>>>(t1, 2048, 128, mW1, 128, 16384, t2, 2048, 128, mb1, 128, 256, 128, 128, 1.f);
        ngemm<0,0,1,1><<<dim3(128,1,16), 256, 0, stream>>>(t2, 2048, 128, mW2, 128, 16384, slots, 2048, 128, mb2, 128, 256, 128, 128, 1.f);
        // block-wise attention over prototypes
        bwa_stat_k<<<16, 256, 0, stream>>>(slots, stat);
        bwa_score_k<<<1024, 256, 0, stream>>>(slots, memf, stat, bwsc);
        bwa_soft_k<<<16, 256, 0, stream>>>(bwsc);
        bwa_out_k<<<2048, 256, 0, stream>>>(bwsc, memf, slots);
    }
    out_k<<<3072, 256, 0, stream>>>(slots, attn, (float*)d_out);
}

// Round 7
// 666.801 us; speedup vs baseline: 15.2565x; 15.2565x over previous
//
#include <hip/hip_runtime.h>

typedef __attribute__((ext_vector_type(8))) short short8;
typedef __attribute__((ext_vector_type(4))) float f32x4;

#define DEV static __device__ __forceinline__

DEV float bfs2f(short s) {
    union { unsigned int u; float f; } c;
    c.u = ((unsigned int)(unsigned short)s) << 16;
    return c.f;
}
DEV short f2bfs(float f) {
    union { float f; unsigned int u; } c;
    c.f = f;
    unsigned int u = c.u;
    return (short)((u + 0x7fffu + ((u >> 16) & 1u)) >> 16);  // RNE
}
DEV int imin(int a, int b) { return a < b ? a : b; }

// ---------------------------------------------------------------------------
// f32 -> bf16 convert
// ---------------------------------------------------------------------------
__global__ __launch_bounds__(256) void cvt_k(const float* __restrict__ src,
                                             short* __restrict__ dst, int n)
{
    int i = blockIdx.x * 256 + threadIdx.x;
    if (i < n) dst[i] = f2bfs(src[i]);
}

// transpose+convert f32 [R,C] -> bf16 [C,R], batched
__global__ __launch_bounds__(256) void transpose_cvt_k(const float* __restrict__ in,
                                                       short* __restrict__ out,
                                                       int R, int C, long ib, long ob)
{
    in  += (long)blockIdx.z * ib;
    out += (long)blockIdx.z * ob;
    __shared__ short t[32][33];
    int c0 = blockIdx.x * 32, r0 = blockIdx.y * 32;
    int x = threadIdx.x & 31, y = threadIdx.x >> 5;  // y: 0..7
    #pragma unroll
    for (int k = 0; k < 32; k += 8) t[y + k][x] = f2bfs(in[(long)(r0 + y + k) * C + (c0 + x)]);
    __syncthreads();
    #pragma unroll
    for (int k = 0; k < 32; k += 8) out[(long)(c0 + y + k) * R + (r0 + x)] = t[x][y + k];
}

// ---------------------------------------------------------------------------
// Tiled MFMA GEMM: C[M,N] = act(scale * A[M,K] * Bt[N,K]^T + bias)
// A, Bt bf16 row-major (K contiguous). 64x64 tile, BK=32, 4 waves.
// ---------------------------------------------------------------------------
template<int OUT_BF16, int RELU, int ACCUM, int HAS_BIAS>
__global__ __launch_bounds__(256) void gemm_bt(
    const short* __restrict__ A, long lda, long aoff,
    const short* __restrict__ Bt, long ldb, long boff,
    void* __restrict__ Cv, long ldc, long coff,
    const float* __restrict__ bias, long biasoff,
    int M, int N, int K, float scale)
{
    const int bz = blockIdx.z;
    A  += (long)bz * aoff;
    Bt += (long)bz * boff;
    const int tid  = threadIdx.x;
    const int wave = tid >> 6, lane = tid & 63;
    const int quad = lane >> 4, l16 = lane & 15;
    const int wr = (wave >> 1) * 32, wc = (wave & 1) * 32;
    const int m0 = blockIdx.x * 64, n0 = blockIdx.y * 64;

    __shared__ __align__(16) short As[64 * 40];
    __shared__ __align__(16) short Bs[64 * 40];

    f32x4 acc[2][2] = {};

    const int lrow = tid >> 2;        // 0..63
    const int lk   = (tid & 3) * 8;   // 0,8,16,24
    const int arow = imin(m0 + lrow, M - 1);
    const int brow = imin(n0 + lrow, N - 1);
    const short* ap = A + (long)arow * lda + lk;
    const short* bp = Bt + (long)brow * ldb + lk;
    short* asd = &As[lrow * 40 + lk];
    short* bsd = &Bs[lrow * 40 + lk];

    for (int k0 = 0; k0 < K; k0 += 32) {
        *(short8*)asd = *(const short8*)(ap + k0);
        *(short8*)bsd = *(const short8*)(bp + k0);
        __syncthreads();
        short8 a0 = *(const short8*)&As[(wr + l16) * 40 + quad * 8];
        short8 a1 = *(const short8*)&As[(wr + 16 + l16) * 40 + quad * 8];
        short8 b0 = *(const short8*)&Bs[(wc + l16) * 40 + quad * 8];
        short8 b1 = *(const short8*)&Bs[(wc + 16 + l16) * 40 + quad * 8];
        acc[0][0] = __builtin_amdgcn_mfma_f32_16x16x32_bf16(a0, b0, acc[0][0], 0, 0, 0);
        acc[0][1] = __builtin_amdgcn_mfma_f32_16x16x32_bf16(a0, b1, acc[0][1], 0, 0, 0);
        acc[1][0] = __builtin_amdgcn_mfma_f32_16x16x32_bf16(a1, b0, acc[1][0], 0, 0, 0);
        acc[1][1] = __builtin_amdgcn_mfma_f32_16x16x32_bf16(a1, b1, acc[1][1], 0, 0, 0);
        __syncthreads();
    }

    #pragma unroll
    for (int sr = 0; sr < 2; sr++) {
        #pragma unroll
        for (int sc = 0; sc < 2; sc++) {
            int gc = n0 + wc + sc * 16 + l16;
            if (gc >= N) continue;
            float bvv = 0.f;
            if (HAS_BIAS) bvv = bias[(long)bz * biasoff + gc];
            #pragma unroll
            for (int r = 0; r < 4; r++) {
                int gr = m0 + wr + sr * 16 + quad * 4 + r;
                if (gr >= M) continue;
                float v = acc[sr][sc][r] * scale + bvv;
                if (RELU) v = fmaxf(v, 0.f);
                long cidx = (long)bz * coff + (long)gr * ldc + gc;
                if (ACCUM)           ((float*)Cv)[cidx] += v;
                else if (OUT_BF16)   ((short*)Cv)[cidx] = f2bfs(v);
                else                 ((float*)Cv)[cidx] = v;
            }
        }
    }
}

// ---------------------------------------------------------------------------
// slots = mu + exp(logsigma) * noise   [256, 2048] f32
// ---------------------------------------------------------------------------
__global__ __launch_bounds__(256) void init_slots_k(const float* __restrict__ noise,
                                                    const float* __restrict__ mu,
                                                    const float* __restrict__ ls,
                                                    float* __restrict__ slots)
{
    int idx = blockIdx.x * 256 + threadIdx.x;  // < 524288
    int d = idx & 2047;
    slots[idx] = mu[d] + expf(ls[d]) * noise[idx];
}

// ---------------------------------------------------------------------------
// LN of inputs over INF=256, affine -> bf16. One wave per row.
// ---------------------------------------------------------------------------
__global__ __launch_bounds__(256) void ln_in_k(const float* __restrict__ in,
                                               const float* __restrict__ g,
                                               const float* __restrict__ b,
                                               short* __restrict__ out)
{
    int row  = blockIdx.x * 4 + (threadIdx.x >> 6);
    int lane = threadIdx.x & 63;
    long off = (long)row * 256 + lane * 4;
    f32x4 v4 = *(const f32x4*)(in + off);
    float v[4] = {v4[0], v4[1], v4[2], v4[3]};
    float s = v[0] + v[1] + v[2] + v[3];
    #pragma unroll
    for (int d = 1; d < 64; d <<= 1) s += __shfl_xor(s, d);
    float mean = s * (1.f / 256.f);
    float sq = 0.f;
    #pragma unroll
    for (int k = 0; k < 4; k++) { float dd = v[k] - mean; sq += dd * dd; }
    #pragma unroll
    for (int d = 1; d < 64; d <<= 1) sq += __shfl_xor(sq, d);
    float inv = rsqrtf(sq * (1.f / 256.f) + 1e-5f);
    short* op = out + off;
    #pragma unroll
    for (int k = 0; k < 4; k++)
        op[k] = f2bfs((v[k] - mean) * inv * g[lane * 4 + k] + b[lane * 4 + k]);
}

// ---------------------------------------------------------------------------
// LN of slots over DIM=2048 -> s_ln bf16; also raw slots -> bf16. Block/row.
// ---------------------------------------------------------------------------
__global__ __launch_bounds__(256) void ln_slots_k(const float* __restrict__ slots,
                                                  const float* __restrict__ g,
                                                  const float* __restrict__ b,
                                                  short* __restrict__ s_ln,
                                                  short* __restrict__ slots_bf)
{
    int row = blockIdx.x, tid = threadIdx.x;
    const float* p = slots + (long)row * 2048 + tid * 8;
    float v[8];
    *(f32x4*)&v[0] = *(const f32x4*)p;
    *(f32x4*)&v[4] = *(const f32x4*)(p + 4);
    float s = 0.f;
    #pragma unroll
    for (int k = 0; k < 8; k++) s += v[k];
    #pragma unroll
    for (int d = 1; d < 64; d <<= 1) s += __shfl_xor(s, d);
    __shared__ float wsum[4], wsq[4];
    int w = tid >> 6, lane = tid & 63;
    if (lane == 0) wsum[w] = s;
    __syncthreads();
    float mean = (wsum[0] + wsum[1] + wsum[2] + wsum[3]) * (1.f / 2048.f);
    float sq = 0.f;
    #pragma unroll
    for (int k = 0; k < 8; k++) { float dd = v[k] - mean; sq += dd * dd; }
    #pragma unroll
    for (int d = 1; d < 64; d <<= 1) sq += __shfl_xor(sq, d);
    if (lane == 0) wsq[w] = sq;
    __syncthreads();
    float var = (wsq[0] + wsq[1] + wsq[2] + wsq[3]) * (1.f / 2048.f);
    float inv = rsqrtf(var + 1e-5f);
    long base = (long)row * 2048 + tid * 8;
    #pragma unroll
    for (int k = 0; k < 8; k++) {
        float xn = (v[k] - mean) * inv;
        s_ln[base + k]     = f2bfs(xn * g[tid * 8 + k] + b[tid * 8 + k]);
        slots_bf[base + k] = f2bfs(v[k]);
    }
}

// ---------------------------------------------------------------------------
// softmax over n (1024, stride 8) per (b,s); +EPS then renorm. Wave per (b,s).
// ---------------------------------------------------------------------------
__global__ __launch_bounds__(64) void softmax_k(const float* __restrict__ dots,
                                                float* __restrict__ attn)
{
    int s = blockIdx.x, b = blockIdx.y, lane = threadIdx.x;
    const float* dp = dots + (long)b * 8192 + s;
    float v[16];
    float mx = -1e30f;
    #pragma unroll
    for (int i = 0; i < 16; i++) { v[i] = dp[(lane + i * 64) * 8]; mx = fmaxf(mx, v[i]); }
    #pragma unroll
    for (int d = 1; d < 64; d <<= 1) mx = fmaxf(mx, __shfl_xor(mx, d));
    float sum = 0.f;
    #pragma unroll
    for (int i = 0; i < 16; i++) { v[i] = expf(v[i] - mx); sum += v[i]; }
    #pragma unroll
    for (int d = 1; d < 64; d <<= 1) sum += __shfl_xor(sum, d);
    float inv = 1.f / sum;
    float sum2 = 0.f;
    #pragma unroll
    for (int i = 0; i < 16; i++) { v[i] = v[i] * inv + 1e-8f; sum2 += v[i]; }
    #pragma unroll
    for (int d = 1; d < 64; d <<= 1) sum2 += __shfl_xor(sum2, d);
    float inv2 = 1.f / sum2;
    float* ap = attn + (long)b * 8192 + s;
    #pragma unroll
    for (int i = 0; i < 16; i++) ap[(lane + i * 64) * 8] = v[i] * inv2;
}

__global__ __launch_bounds__(256) void zero_k(float* __restrict__ p)
{
    p[blockIdx.x * 256 + threadIdx.x] = 0.f;
}

// u'[b,s,i] = sum_n attn[b,n,s] * x_bf[b,n,i]  (n-chunks, atomic accum)
__global__ __launch_bounds__(256) void uprime_k(const float* __restrict__ attn,
                                                const short* __restrict__ x,
                                                float* __restrict__ up)
{
    int b = blockIdx.y, chunk = blockIdx.x, tid = threadIdx.x;
    int n0 = chunk * 128;
    const short* xp = x + ((long)b * 1024 + n0) * 256 + tid;
    const float* ap = attn + ((long)b * 1024 + n0) * 8;
    float acc[8] = {0, 0, 0, 0, 0, 0, 0, 0};
    for (int n = 0; n < 128; n++) {
        float xv = bfs2f(xp[n * 256]);
        #pragma unroll
        for (int s = 0; s < 8; s++) acc[s] += ap[n * 8 + s] * xv;
    }
    float* dst = up + (long)b * 8 * 256;
    #pragma unroll
    for (int s = 0; s < 8; s++) atomicAdd(dst + s * 256 + tid, acc[s]);
}

// ---------------------------------------------------------------------------
// GRU gates: slots = (1-z)*tanh(in + r*hn) + z*h
// ---------------------------------------------------------------------------
__global__ __launch_bounds__(256) void gru_k(const float* __restrict__ gi,
                                             const float* __restrict__ gh,
                                             const float* __restrict__ bih,
                                             const float* __restrict__ bhh,
                                             float* __restrict__ slots)
{
    int idx = blockIdx.x * 256 + threadIdx.x;  // < 524288
    int r = idx >> 11, c = idx & 2047;
    int nb = c >> 7, j = c & 127;
    long gbase = (long)r * 6144 + nb * 384 + j;
    int bbase = nb * 384 + j;
    float ir  = gi[gbase]       + bih[bbase];
    float iz  = gi[gbase + 128] + bih[bbase + 128];
    float in_ = gi[gbase + 256] + bih[bbase + 256];
    float hr  = gh[gbase]       + bhh[bbase];
    float hz  = gh[gbase + 128] + bhh[bbase + 128];
    float hn  = gh[gbase + 256] + bhh[bbase + 256];
    float rg = 1.f / (1.f + expf(-(ir + hr)));
    float zg = 1.f / (1.f + expf(-(iz + hz)));
    float nn = tanhf(in_ + rg * hn);
    float h = slots[idx];
    slots[idx] = (1.f - zg) * nn + zg * h;
}

// ---------------------------------------------------------------------------
// BlockLayerNorm over 128-blocks, f32 in; bf16 or f32 out. Wave per row.
// ---------------------------------------------------------------------------
template<int OUT_BF16>
__global__ __launch_bounds__(64) void bln_k(const float* __restrict__ in, void* __restrict__ out)
{
    long row = blockIdx.x;
    int lane = threadIdx.x;
    const float* p = in + row * 128 + lane * 2;
    float v0 = p[0], v1 = p[1];
    float s = v0 + v1, sq = v0 * v0 + v1 * v1;
    #pragma unroll
    for (int d = 1; d < 64; d <<= 1) { s += __shfl_xor(s, d); sq += __shfl_xor(sq, d); }
    float mean = s * (1.f / 128.f);
    float var = sq * (1.f / 128.f) - mean * mean;
    float inv = rsqrtf(var + 1e-5f);
    long o = row * 128 + lane * 2;
    if (OUT_BF16) {
        ((short*)out)[o]     = f2bfs((v0 - mean) * inv);
        ((short*)out)[o + 1] = f2bfs((v1 - mean) * inv);
    } else {
        ((float*)out)[o]     = (v0 - mean) * inv;
        ((float*)out)[o + 1] = (v1 - mean) * inv;
    }
}

// ---------------------------------------------------------------------------
// Block-wise attention over prototypes (fused BLN of slots + q scale).
// block = (nb, b); slots updated in place.
// ---------------------------------------------------------------------------
__global__ __launch_bounds__(256) void bwa_k(float* __restrict__ slots,
                                             const float* __restrict__ mem)
{
    int nb = blockIdx.x, b = blockIdx.y, tid = threadIdx.x;
    __shared__ float qn[8 * 128];
    __shared__ float ml[64 * 129];
    __shared__ float sc[8 * 64];

    for (int idx = tid; idx < 64 * 128; idx += 256) {
        int p = idx >> 7, j = idx & 127;
        ml[p * 129 + j] = mem[(long)(p * 16 + nb) * 128 + j];
    }
    {
        int t = tid >> 5;
        int j0 = (tid & 31) * 4;
        const float* src = slots + (long)(b * 8 + t) * 2048 + nb * 128 + j0;
        float v0 = src[0], v1 = src[1], v2 = src[2], v3 = src[3];
        float s = v0 + v1 + v2 + v3;
        float sq = v0 * v0 + v1 * v1 + v2 * v2 + v3 * v3;
        #pragma unroll
        for (int d = 1; d < 32; d <<= 1) { s += __shfl_xor(s, d); sq += __shfl_xor(sq, d); }
        float mean = s * (1.f / 128.f);
        float var = sq * (1.f / 128.f) - mean * mean;
        float inv = rsqrtf(var + 1e-5f) * 0.08838834764831845f;  // BD^-0.5 folded in
        qn[t * 128 + j0]     = (v0 - mean) * inv;
        qn[t * 128 + j0 + 1] = (v1 - mean) * inv;
        qn[t * 128 + j0 + 2] = (v2 - mean) * inv;
        qn[t * 128 + j0 + 3] = (v3 - mean) * inv;
    }
    __syncthreads();
    for (int idx = tid; idx < 512; idx += 256) {
        int t = idx >> 6, p = idx & 63;
        const float* qr = &qn[t * 128];
        const float* mr = &ml[p * 129];
        float acc = 0.f;
        for (int j = 0; j < 128; j++) acc += qr[j] * mr[j];
        sc[t * 64 + p] = acc;
    }
    __syncthreads();
    {
        int w = tid >> 6, lane = tid & 63;
        for (int t = w; t < 8; t += 4) {
            float v = sc[t * 64 + lane];
            float m = v;
            #pragma unroll
            for (int d = 1; d < 64; d <<= 1) m = fmaxf(m, __shfl_xor(m, d));
            float e = expf(v - m);
            float ssum = e;
            #pragma unroll
            for (int d = 1; d < 64; d <<= 1) ssum += __shfl_xor(ssum, d);
            sc[t * 64 + lane] = e / ssum;
        }
    }
    __syncthreads();
    {
        int t = tid >> 5, j0 = (tid & 31) * 4;
        float a0 = 0, a1 = 0, a2 = 0, a3 = 0;
        for (int p = 0; p < 64; p++) {
            float a = sc[t * 64 + p];
            const float* mr = &ml[p * 129 + j0];
            a0 += a * mr[0]; a1 += a * mr[1]; a2 += a * mr[2]; a3 += a * mr[3];
        }
        float* dst = slots + (long)(b * 8 + t) * 2048 + nb * 128 + j0;
        dst[0] = a0; dst[1] = a1; dst[2] = a2; dst[3] = a3;
    }
}

// OUTPUT IS FLOAT32
__global__ __launch_bounds__(256) void out_k(const float* __restrict__ slots,
                                             const float* __restrict__ attn,
                                             float* __restrict__ out)
{
    int idx = blockIdx.x * 256 + threadIdx.x;  // < 786432
    out[idx] = (idx < 524288) ? slots[idx] : attn[idx - 524288];
}

// ===========================================================================
extern "C" void kernel_launch(void* const* d_in, const int* in_sizes, int n_in,
                              void* d_out, int out_size, void* d_ws, size_t ws_size,
                              hipStream_t stream)
{
    (void)in_sizes; (void)n_in; (void)out_size; (void)ws_size;
    const float* inputs = (const float*)d_in[0];
    const float* noise  = (const float*)d_in[1];
    const float* smu    = (const float*)d_in[2];
    const float* sls    = (const float*)d_in[3];
    const float* Wq     = (const float*)d_in[4];
    const float* bq     = (const float*)d_in[5];
    const float* Wk     = (const float*)d_in[6];
    /* d_in[7] = bk: softmax(axis=n)-invariant; dropped */
    const float* Wv     = (const float*)d_in[8];
    const float* bv     = (const float*)d_in[9];
    const float* gWih   = (const float*)d_in[10];
    const float* gWhh   = (const float*)d_in[11];
    const float* gbih   = (const float*)d_in[12];
    const float* gbhh   = (const float*)d_in[13];
    const float* mW1    = (const float*)d_in[14];
    const float* mb1    = (const float*)d_in[15];
    const float* mW2    = (const float*)d_in[16];
    const float* mb2    = (const float*)d_in[17];
    const float* cvec   = (const float*)d_in[18];
    const float* cW1    = (const float*)d_in[19];
    const float* cb1    = (const float*)d_in[20];
    const float* cW2    = (const float*)d_in[21];
    const float* cb2    = (const float*)d_in[22];
    const float* cW3    = (const float*)d_in[23];
    const float* cb3    = (const float*)d_in[24];
    const float* cW4    = (const float*)d_in[25];
    const float* cb4    = (const float*)d_in[26];
    const float* nig    = (const float*)d_in[27];
    const float* nib    = (const float*)d_in[28];
    const float* nsg    = (const float*)d_in[29];
    const float* nsb    = (const float*)d_in[30];

    char* w = (char*)d_ws;
    auto take = [&](size_t bytes) -> char* {
        char* p = w;
        w += (bytes + 255) & ~(size_t)255;
        return p;
    };

    float* slots   = (float*)take((size_t)524288 * 4);
    short* xbf     = (short*)take((size_t)32768 * 256 * 2);
    short* Wqt     = (short*)take((size_t)2048 * 2048 * 2);
    short* WvT     = (short*)take((size_t)2048 * 256 * 2);
    short* Wkbf    = (short*)take((size_t)256 * 2048 * 2);
    short* mW1T    = (short*)take((size_t)16 * 128 * 128 * 2);
    short* mW2T    = (short*)take((size_t)16 * 128 * 128 * 2);
    short* gWihbf  = (short*)take((size_t)16 * 384 * 128 * 2);
    short* gWhhbf  = (short*)take((size_t)16 * 384 * 128 * 2);
    float* memf    = (float*)take((size_t)1024 * 128 * 4);
    float* attn    = (float*)take((size_t)32 * 1024 * 8 * 4);
    short* cvecbf  = (short*)take((size_t)1024 * 128 * 2);
    short* cW1T    = (short*)take((size_t)512 * 128 * 2);
    short* cW2T    = (short*)take((size_t)512 * 512 * 2);
    short* cW3T    = (short*)take((size_t)512 * 512 * 2);
    short* cW4T    = (short*)take((size_t)128 * 512 * 2);
    short* hA      = (short*)take((size_t)1024 * 512 * 2);
    short* hB      = (short*)take((size_t)1024 * 512 * 2);
    float* h4      = (float*)take((size_t)1024 * 128 * 4);
    short* s_ln    = (short*)take((size_t)256 * 2048 * 2);
    short* slotsbf = (short*)take((size_t)256 * 2048 * 2);
    short* qbf     = (short*)take((size_t)256 * 2048 * 2);
    short* kqT     = (short*)take((size_t)256 * 256 * 2);
    float* dots    = (float*)take((size_t)32 * 1024 * 8 * 4);
    float* up      = (float*)take((size_t)256 * 256 * 4);
    short* upbf    = (short*)take((size_t)256 * 256 * 2);
    short* updbf   = (short*)take((size_t)256 * 2048 * 2);
    float* gi      = (float*)take((size_t)256 * 6144 * 4);
    float* gh      = (float*)take((size_t)256 * 6144 * 4);
    short* t1      = (short*)take((size_t)256 * 2048 * 2);
    short* t2      = (short*)take((size_t)256 * 2048 * 2);

    // --- weight conversions / transposes (once per call) -------------------
    cvt_k<<<2048, 256, 0, stream>>>(Wk, Wkbf, 524288);
    cvt_k<<<3072, 256, 0, stream>>>(gWih, gWihbf, 786432);
    cvt_k<<<3072, 256, 0, stream>>>(gWhh, gWhhbf, 786432);
    cvt_k<<<512, 256, 0, stream>>>(cvec, cvecbf, 131072);
    transpose_cvt_k<<<dim3(64, 64, 1), 256, 0, stream>>>(Wq, Wqt, 2048, 2048, 0, 0);
    transpose_cvt_k<<<dim3(64, 8, 1),  256, 0, stream>>>(Wv, WvT, 256, 2048, 0, 0);
    transpose_cvt_k<<<dim3(4, 4, 16),  256, 0, stream>>>(mW1, mW1T, 128, 128, 16384, 16384);
    transpose_cvt_k<<<dim3(4, 4, 16),  256, 0, stream>>>(mW2, mW2T, 128, 128, 16384, 16384);
    transpose_cvt_k<<<dim3(16, 4, 1),  256, 0, stream>>>(cW1, cW1T, 128, 512, 0, 0);
    transpose_cvt_k<<<dim3(16, 16, 1), 256, 0, stream>>>(cW2, cW2T, 512, 512, 0, 0);
    transpose_cvt_k<<<dim3(16, 16, 1), 256, 0, stream>>>(cW3, cW3T, 512, 512, 0, 0);
    transpose_cvt_k<<<dim3(4, 16, 1),  256, 0, stream>>>(cW4, cW4T, 512, 128, 0, 0);

    init_slots_k<<<2048, 256, 0, stream>>>(noise, smu, sls, slots);
    ln_in_k<<<8192, 256, 0, stream>>>(inputs, nig, nib, xbf);

    // --- concept memory (iteration-invariant: compute once) ----------------
    gemm_bt<1,1,0,1><<<dim3(16, 8, 1), 256, 0, stream>>>(cvecbf, 128, 0, cW1T, 128, 0, hA, 512, 0, cb1, 0, 1024, 512, 128, 1.f);
    gemm_bt<1,1,0,1><<<dim3(16, 8, 1), 256, 0, stream>>>(hA, 512, 0, cW2T, 512, 0, hB, 512, 0, cb2, 0, 1024, 512, 512, 1.f);
    gemm_bt<1,1,0,1><<<dim3(16, 8, 1), 256, 0, stream>>>(hB, 512, 0, cW3T, 512, 0, hA, 512, 0, cb3, 0, 1024, 512, 512, 1.f);
    gemm_bt<0,0,0,1><<<dim3(16, 2, 1), 256, 0, stream>>>(hA, 512, 0, cW4T, 512, 0, h4, 128, 0, cb4, 0, 1024, 128, 512, 1.f);
    bln_k<0><<<1024, 64, 0, stream>>>(h4, memf);

    for (int it = 0; it < 3; ++it) {
        ln_slots_k<<<256, 256, 0, stream>>>(slots, nsg, nsb, s_ln, slotsbf);
        // q = LN(slots)@Wq + bq
        gemm_bt<1,0,0,1><<<dim3(4, 32, 1), 256, 0, stream>>>(s_ln, 2048, 0, Wqt, 2048, 0, qbf, 2048, 0, bq, 0, 256, 2048, 2048, 1.f);
        // kqT[bs,i] = q @ Wk^T  (k never materialized)
        gemm_bt<1,0,0,0><<<dim3(4, 4, 1), 256, 0, stream>>>(qbf, 2048, 0, Wkbf, 2048, 0, kqT, 256, 0, nullptr, 0, 256, 256, 2048, 1.f);
        // dots[b,n,s] = scale * x[b] @ kqT[b]^T
        gemm_bt<0,0,0,0><<<dim3(16, 1, 32), 256, 0, stream>>>(xbf, 256, 262144, kqT, 256, 2048, dots, 8, 8192, nullptr, 0, 1024, 8, 256, 0.022097086912079608f);
        softmax_k<<<dim3(8, 32), 64, 0, stream>>>(dots, attn);
        zero_k<<<256, 256, 0, stream>>>(up);
        uprime_k<<<dim3(8, 32), 256, 0, stream>>>(attn, xbf, up);
        cvt_k<<<256, 256, 0, stream>>>(up, upbf, 65536);
        // updates = u' @ Wv + bv  (sum_n attn == 1)
        gemm_bt<1,0,0,1><<<dim3(4, 32, 1), 256, 0, stream>>>(upbf, 256, 0, WvT, 256, 0, updbf, 2048, 0, bv, 0, 256, 2048, 256, 1.f);
        // GRU gates (block-diagonal, batched over 16 blocks)
        gemm_bt<0,0,0,0><<<dim3(4, 6, 16), 256, 0, stream>>>(updbf, 2048, 128, gWihbf, 128, 49152, gi, 6144, 384, nullptr, 0, 256, 384, 128, 1.f);
        gemm_bt<0,0,0,0><<<dim3(4, 6, 16), 256, 0, stream>>>(slotsbf, 2048, 128, gWhhbf, 128, 49152, gh, 6144, 384, nullptr, 0, 256, 384, 128, 1.f);
        gru_k<<<2048, 256, 0, stream>>>(gi, gh, gbih, gbhh, slots);
        // residual block-MLP
        bln_k<1><<<4096, 64, 0, stream>>>(slots, t1);
        gemm_bt<1,1,0,1><<<dim3(4, 2, 16), 256, 0, stream>>>(t1, 2048, 128, mW1T, 128, 16384, t2, 2048, 128, mb1, 128, 256, 128, 128, 1.f);
        gemm_bt<0,0,1,1><<<dim3(4, 2, 16), 256, 0, stream>>>(t2, 2048, 128, mW2T, 128, 16384, slots, 2048, 128, mb2, 128, 256, 128, 128, 1.f);
        // block-wise attention over prototypes (in-place slot update)
        bwa_k<<<dim3(16, 32), 256, 0, stream>>>(slots, memf);
    }
    out_k<<<3072, 256, 0, stream>>>(slots, attn, (float*)d_out);
}

// Round 8
// 521.588 us; speedup vs baseline: 19.5040x; 1.2784x over previous
//
#include <hip/hip_runtime.h>

typedef __attribute__((ext_vector_type(8))) short short8;
typedef __attribute__((ext_vector_type(4))) float f32x4;

#define DEV static __device__ __forceinline__

DEV float bfs2f(short s) {
    union { unsigned int u; float f; } c;
    c.u = ((unsigned int)(unsigned short)s) << 16;
    return c.f;
}
DEV short f2bfs(float f) {
    union { float f; unsigned int u; } c;
    c.f = f;
    unsigned int u = c.u;
    return (short)((u + 0x7fffu + ((u >> 16) & 1u)) >> 16);  // RNE
}
DEV int imin(int a, int b) { return a < b ? a : b; }

// ---------------------------------------------------------------------------
// Fused f32->bf16 convert of all plain weights (one launch).
// Segments: Wq 4194304 | Wk 524288 | Wv 524288 | gWih 786432 | gWhh 786432 | cvec 131072
// ---------------------------------------------------------------------------
__global__ __launch_bounds__(256) void cvt_all_k(
    const float* __restrict__ Wq, const float* __restrict__ Wk, const float* __restrict__ Wv,
    const float* __restrict__ gih, const float* __restrict__ ghh, const float* __restrict__ cv,
    short* __restrict__ dWq, short* __restrict__ dWk, short* __restrict__ dWv,
    short* __restrict__ dgih, short* __restrict__ dghh, short* __restrict__ dcv)
{
    long i = (long)blockIdx.x * 256 + threadIdx.x;
    const float* s; short* d; long o;
    if      (i < 4194304) { s = Wq;  d = dWq;  o = i; }
    else if (i < 4718592) { s = Wk;  d = dWk;  o = i - 4194304; }
    else if (i < 5242880) { s = Wv;  d = dWv;  o = i - 4718592; }
    else if (i < 6029312) { s = gih; d = dgih; o = i - 5242880; }
    else if (i < 6815744) { s = ghh; d = dghh; o = i - 6029312; }
    else if (i < 6946816) { s = cv;  d = dcv;  o = i - 6815744; }
    else return;
    d[o] = f2bfs(s[o]);
}

// transpose+convert f32 [R,C] -> bf16 [C,R], batched
__global__ __launch_bounds__(256) void transpose_cvt_k(const float* __restrict__ in,
                                                       short* __restrict__ out,
                                                       int R, int C, long ib, long ob)
{
    in  += (long)blockIdx.z * ib;
    out += (long)blockIdx.z * ob;
    __shared__ short t[32][33];
    int c0 = blockIdx.x * 32, r0 = blockIdx.y * 32;
    int x = threadIdx.x & 31, y = threadIdx.x >> 5;
    #pragma unroll
    for (int k = 0; k < 32; k += 8) t[y + k][x] = f2bfs(in[(long)(r0 + y + k) * C + (c0 + x)]);
    __syncthreads();
    #pragma unroll
    for (int k = 0; k < 32; k += 8) out[(long)(c0 + y + k) * R + (r0 + x)] = t[x][y + k];
}

__global__ __launch_bounds__(256) void zero_k(float* __restrict__ p, int n)
{
    int i = blockIdx.x * 256 + threadIdx.x;
    if (i < n) p[i] = 0.f;
}

// b1g[nb,g] = sum_j bv[nb*128+j] * gWih[nb,g,j]
__global__ __launch_bounds__(256) void b1g_k(const float* __restrict__ bv,
                                             const float* __restrict__ gWih,
                                             float* __restrict__ b1g)
{
    int t = blockIdx.x * 256 + threadIdx.x;
    if (t >= 6144) return;
    int nb = t / 384, g = t % 384;
    const float* wrow = gWih + (long)nb * 49152 + (long)g * 128;
    const float* bp = bv + nb * 128;
    float acc = 0.f;
    for (int j = 0; j < 128; j++) acc += bp[j] * wrow[j];
    b1g[t] = acc;
}

// c1[i] = sum_d bq[d] * Wk[i,d]   (one block per i)
__global__ __launch_bounds__(256) void c1_k(const float* __restrict__ bq,
                                            const float* __restrict__ Wk,
                                            float* __restrict__ c1)
{
    int i = blockIdx.x, tid = threadIdx.x;
    const float* row = Wk + (long)i * 2048;
    float acc = 0.f;
    for (int d = tid; d < 2048; d += 256) acc += bq[d] * row[d];
    #pragma unroll
    for (int d = 1; d < 64; d <<= 1) acc += __shfl_xor(acc, d);
    __shared__ float red[4];
    int w = tid >> 6;
    if ((tid & 63) == 0) red[w] = acc;
    __syncthreads();
    if (tid == 0) c1[i] = red[0] + red[1] + red[2] + red[3];
}

// ---------------------------------------------------------------------------
// Tiled MFMA GEMM with register-prefetch pipeline.
// C[M,N] = act(scale * A[M,K] * Bt[N,K]^T + bias)
// OUT_MODE: 0=f32 store, 1=bf16 store, 2=f32 +=, 3=f32 atomicAdd
// A_F32/B_F32: operand is f32, converted to bf16 during LDS staging.
// SPLITK>1: blockIdx.z = K-slice (batch unsupported); bias added by slice 0.
// ---------------------------------------------------------------------------
template<int OUT_MODE, int RELU, int HAS_BIAS, int A_F32, int B_F32, int SPLITK>
__global__ __launch_bounds__(256) void gemm_bt(
    const void* __restrict__ Av, long lda, long aoff,
    const void* __restrict__ Btv, long ldb, long boff,
    void* __restrict__ Cv, long ldc, long coff,
    const float* __restrict__ bias, long biasoff,
    int M, int N, int K, float scale)
{
    const int bz = blockIdx.z;
    long abase, bbase, cbase;
    int kbeg, kend, addbias;
    if (SPLITK > 1) {
        int ks = K / SPLITK;
        kbeg = bz * ks; kend = kbeg + ks;
        abase = 0; bbase = 0; cbase = 0; addbias = (bz == 0);
    } else {
        kbeg = 0; kend = K;
        abase = (long)bz * aoff; bbase = (long)bz * boff; cbase = (long)bz * coff;
        addbias = 1;
    }
    const int tid  = threadIdx.x;
    const int wave = tid >> 6, lane = tid & 63;
    const int quad = lane >> 4, l16 = lane & 15;
    const int wr = (wave >> 1) * 32, wc = (wave & 1) * 32;
    const int m0 = blockIdx.x * 64, n0 = blockIdx.y * 64;

    __shared__ __align__(16) short As[64 * 40];
    __shared__ __align__(16) short Bs[64 * 40];

    f32x4 acc[2][2] = {};

    const int lrow = tid >> 2;        // 0..63
    const int lk   = (tid & 3) * 8;   // 0,8,16,24
    const int arow = imin(m0 + lrow, M - 1);
    const int brow = imin(n0 + lrow, N - 1);
    short* asd = &As[lrow * 40 + lk];
    short* bsd = &Bs[lrow * 40 + lk];

    short8 arS = {}, brS = {};
    f32x4 arF0 = {}, arF1 = {}, brF0 = {}, brF1 = {};

    auto loadA = [&](int k0) {
        if (A_F32) {
            const float* p = (const float*)Av + abase + (long)arow * lda + lk + k0;
            arF0 = *(const f32x4*)p; arF1 = *(const f32x4*)(p + 4);
        } else {
            arS = *(const short8*)((const short*)Av + abase + (long)arow * lda + lk + k0);
        }
    };
    auto loadB = [&](int k0) {
        if (B_F32) {
            const float* p = (const float*)Btv + bbase + (long)brow * ldb + lk + k0;
            brF0 = *(const f32x4*)p; brF1 = *(const f32x4*)(p + 4);
        } else {
            brS = *(const short8*)((const short*)Btv + bbase + (long)brow * ldb + lk + k0);
        }
    };
    auto stage = [&]() {
        if (A_F32) {
            short8 t;
            #pragma unroll
            for (int j = 0; j < 4; j++) { t[j] = f2bfs(arF0[j]); t[j + 4] = f2bfs(arF1[j]); }
            *(short8*)asd = t;
        } else *(short8*)asd = arS;
        if (B_F32) {
            short8 t;
            #pragma unroll
            for (int j = 0; j < 4; j++) { t[j] = f2bfs(brF0[j]); t[j + 4] = f2bfs(brF1[j]); }
            *(short8*)bsd = t;
        } else *(short8*)bsd = brS;
    };

    loadA(kbeg); loadB(kbeg);
    for (int k0 = kbeg; k0 < kend; k0 += 32) {
        stage();
        __syncthreads();
        if (k0 + 32 < kend) { loadA(k0 + 32); loadB(k0 + 32); }  // prefetch next tile
        short8 a0 = *(const short8*)&As[(wr + l16) * 40 + quad * 8];
        short8 a1 = *(const short8*)&As[(wr + 16 + l16) * 40 + quad * 8];
        short8 b0 = *(const short8*)&Bs[(wc + l16) * 40 + quad * 8];
        short8 b1 = *(const short8*)&Bs[(wc + 16 + l16) * 40 + quad * 8];
        acc[0][0] = __builtin_amdgcn_mfma_f32_16x16x32_bf16(a0, b0, acc[0][0], 0, 0, 0);
        acc[0][1] = __builtin_amdgcn_mfma_f32_16x16x32_bf16(a0, b1, acc[0][1], 0, 0, 0);
        acc[1][0] = __builtin_amdgcn_mfma_f32_16x16x32_bf16(a1, b0, acc[1][0], 0, 0, 0);
        acc[1][1] = __builtin_amdgcn_mfma_f32_16x16x32_bf16(a1, b1, acc[1][1], 0, 0, 0);
        __syncthreads();
    }

    #pragma unroll
    for (int sr = 0; sr < 2; sr++) {
        #pragma unroll
        for (int sc = 0; sc < 2; sc++) {
            int gc = n0 + wc + sc * 16 + l16;
            if (gc >= N) continue;
            float bvv = 0.f;
            if (HAS_BIAS && addbias)
                bvv = bias[(SPLITK > 1 ? 0 : (long)bz * biasoff) + gc];
            #pragma unroll
            for (int r = 0; r < 4; r++) {
                int gr = m0 + wr + sr * 16 + quad * 4 + r;
                if (gr >= M) continue;
                float v = acc[sr][sc][r] * scale + bvv;
                if (RELU) v = fmaxf(v, 0.f);
                long cidx = cbase + (long)gr * ldc + gc;
                if (OUT_MODE == 0)      ((float*)Cv)[cidx] = v;
                else if (OUT_MODE == 1) ((short*)Cv)[cidx] = f2bfs(v);
                else if (OUT_MODE == 2) ((float*)Cv)[cidx] += v;
                else                    atomicAdd((float*)Cv + cidx, v);
            }
        }
    }
}

// ---------------------------------------------------------------------------
// slots = mu + exp(logsigma) * noise
// ---------------------------------------------------------------------------
__global__ __launch_bounds__(256) void init_slots_k(const float* __restrict__ noise,
                                                    const float* __restrict__ mu,
                                                    const float* __restrict__ ls,
                                                    float* __restrict__ slots)
{
    int idx = blockIdx.x * 256 + threadIdx.x;
    int d = idx & 2047;
    slots[idx] = mu[d] + expf(ls[d]) * noise[idx];
}

// ---------------------------------------------------------------------------
// LN of inputs over INF=256, affine -> bf16. One wave per row.
// ---------------------------------------------------------------------------
__global__ __launch_bounds__(256) void ln_in_k(const float* __restrict__ in,
                                               const float* __restrict__ g,
                                               const float* __restrict__ b,
                                               short* __restrict__ out)
{
    int row  = blockIdx.x * 4 + (threadIdx.x >> 6);
    int lane = threadIdx.x & 63;
    long off = (long)row * 256 + lane * 4;
    f32x4 v4 = *(const f32x4*)(in + off);
    float v[4] = {v4[0], v4[1], v4[2], v4[3]};
    float s = v[0] + v[1] + v[2] + v[3];
    #pragma unroll
    for (int d = 1; d < 64; d <<= 1) s += __shfl_xor(s, d);
    float mean = s * (1.f / 256.f);
    float sq = 0.f;
    #pragma unroll
    for (int k = 0; k < 4; k++) { float dd = v[k] - mean; sq += dd * dd; }
    #pragma unroll
    for (int d = 1; d < 64; d <<= 1) sq += __shfl_xor(sq, d);
    float inv = rsqrtf(sq * (1.f / 256.f) + 1e-5f);
    short* op = out + off;
    #pragma unroll
    for (int k = 0; k < 4; k++)
        op[k] = f2bfs((v[k] - mean) * inv * g[lane * 4 + k] + b[lane * 4 + k]);
}

// ---------------------------------------------------------------------------
// LN of slots over 2048 -> s_ln bf16; raw slots -> bf16; zero kqf. Block/row.
// ---------------------------------------------------------------------------
__global__ __launch_bounds__(256) void ln_slots_k(const float* __restrict__ slots,
                                                  const float* __restrict__ g,
                                                  const float* __restrict__ b,
                                                  short* __restrict__ s_ln,
                                                  short* __restrict__ slots_bf,
                                                  float* __restrict__ kqf)
{
    int row = blockIdx.x, tid = threadIdx.x;
    kqf[row * 256 + tid] = 0.f;  // pre-zero for split-K atomic kq GEMM
    const float* p = slots + (long)row * 2048 + tid * 8;
    float v[8];
    *(f32x4*)&v[0] = *(const f32x4*)p;
    *(f32x4*)&v[4] = *(const f32x4*)(p + 4);
    float s = 0.f;
    #pragma unroll
    for (int k = 0; k < 8; k++) s += v[k];
    #pragma unroll
    for (int d = 1; d < 64; d <<= 1) s += __shfl_xor(s, d);
    __shared__ float wsum[4], wsq[4];
    int w = tid >> 6, lane = tid & 63;
    if (lane == 0) wsum[w] = s;
    __syncthreads();
    float mean = (wsum[0] + wsum[1] + wsum[2] + wsum[3]) * (1.f / 2048.f);
    float sq = 0.f;
    #pragma unroll
    for (int k = 0; k < 8; k++) { float dd = v[k] - mean; sq += dd * dd; }
    #pragma unroll
    for (int d = 1; d < 64; d <<= 1) sq += __shfl_xor(sq, d);
    if (lane == 0) wsq[w] = sq;
    __syncthreads();
    float var = (wsq[0] + wsq[1] + wsq[2] + wsq[3]) * (1.f / 2048.f);
    float inv = rsqrtf(var + 1e-5f);
    long base = (long)row * 2048 + tid * 8;
    #pragma unroll
    for (int k = 0; k < 8; k++) {
        float xn = (v[k] - mean) * inv;
        s_ln[base + k]     = f2bfs(xn * g[tid * 8 + k] + b[tid * 8 + k]);
        slots_bf[base + k] = f2bfs(v[k]);
    }
}

// ---------------------------------------------------------------------------
// softmax over n (1024, stride 8) per (b,s); +EPS renorm; zeroes up[b,s,:].
// ---------------------------------------------------------------------------
__global__ __launch_bounds__(64) void softmax_k(const float* __restrict__ dots,
                                                float* __restrict__ attn,
                                                float* __restrict__ up)
{
    int s = blockIdx.x, b = blockIdx.y, lane = threadIdx.x;
    {
        float* z = up + (long)b * 2048 + s * 256 + lane * 4;
        z[0] = 0.f; z[1] = 0.f; z[2] = 0.f; z[3] = 0.f;
    }
    const float* dp = dots + (long)b * 8192 + s;
    float v[16];
    float mx = -1e30f;
    #pragma unroll
    for (int i = 0; i < 16; i++) { v[i] = dp[(lane + i * 64) * 8]; mx = fmaxf(mx, v[i]); }
    #pragma unroll
    for (int d = 1; d < 64; d <<= 1) mx = fmaxf(mx, __shfl_xor(mx, d));
    float sum = 0.f;
    #pragma unroll
    for (int i = 0; i < 16; i++) { v[i] = expf(v[i] - mx); sum += v[i]; }
    #pragma unroll
    for (int d = 1; d < 64; d <<= 1) sum += __shfl_xor(sum, d);
    float inv = 1.f / sum;
    float sum2 = 0.f;
    #pragma unroll
    for (int i = 0; i < 16; i++) { v[i] = v[i] * inv + 1e-8f; sum2 += v[i]; }
    #pragma unroll
    for (int d = 1; d < 64; d <<= 1) sum2 += __shfl_xor(sum2, d);
    float inv2 = 1.f / sum2;
    float* ap = attn + (long)b * 8192 + s;
    #pragma unroll
    for (int i = 0; i < 16; i++) ap[(lane + i * 64) * 8] = v[i] * inv2;
}

// u'[b,s,i] = sum_n attn[b,n,s] * x_bf[b,n,i]  (n-chunks, atomic accum)
__global__ __launch_bounds__(256) void uprime_k(const float* __restrict__ attn,
                                                const short* __restrict__ x,
                                                float* __restrict__ up)
{
    int b = blockIdx.y, chunk = blockIdx.x, tid = threadIdx.x;
    int n0 = chunk * 128;
    const short* xp = x + ((long)b * 1024 + n0) * 256 + tid;
    const float* ap = attn + ((long)b * 1024 + n0) * 8;
    float acc[8] = {0, 0, 0, 0, 0, 0, 0, 0};
    for (int n = 0; n < 128; n++) {
        float xv = bfs2f(xp[n * 256]);
        #pragma unroll
        for (int s = 0; s < 8; s++) acc[s] += ap[n * 8 + s] * xv;
    }
    float* dst = up + (long)b * 8 * 256;
    #pragma unroll
    for (int s = 0; s < 8; s++) atomicAdd(dst + s * 256 + tid, acc[s]);
}

// ---------------------------------------------------------------------------
// GRU gates: slots = (1-z)*tanh(in + r*hn) + z*h
// ---------------------------------------------------------------------------
__global__ __launch_bounds__(256) void gru_k(const float* __restrict__ gi,
                                             const float* __restrict__ gh,
                                             const float* __restrict__ bih,
                                             const float* __restrict__ bhh,
                                             float* __restrict__ slots)
{
    int idx = blockIdx.x * 256 + threadIdx.x;
    int r = idx >> 11, c = idx & 2047;
    int nb = c >> 7, j = c & 127;
    long gbase = (long)r * 6144 + nb * 384 + j;
    int bbase = nb * 384 + j;
    float ir  = gi[gbase]       + bih[bbase];
    float iz  = gi[gbase + 128] + bih[bbase + 128];
    float in_ = gi[gbase + 256] + bih[bbase + 256];
    float hr  = gh[gbase]       + bhh[bbase];
    float hz  = gh[gbase + 128] + bhh[bbase + 128];
    float hn  = gh[gbase + 256] + bhh[bbase + 256];
    float rg = 1.f / (1.f + expf(-(ir + hr)));
    float zg = 1.f / (1.f + expf(-(iz + hz)));
    float nn = tanhf(in_ + rg * hn);
    float h = slots[idx];
    slots[idx] = (1.f - zg) * nn + zg * h;
}

// ---------------------------------------------------------------------------
// BlockLayerNorm over 128-blocks, f32 in; bf16 or f32 out. Wave per row.
// ---------------------------------------------------------------------------
template<int OUT_BF16>
__global__ __launch_bounds__(64) void bln_k(const float* __restrict__ in, void* __restrict__ out)
{
    long row = blockIdx.x;
    int lane = threadIdx.x;
    const float* p = in + row * 128 + lane * 2;
    float v0 = p[0], v1 = p[1];
    float s = v0 + v1, sq = v0 * v0 + v1 * v1;
    #pragma unroll
    for (int d = 1; d < 64; d <<= 1) { s += __shfl_xor(s, d); sq += __shfl_xor(sq, d); }
    float mean = s * (1.f / 128.f);
    float var = sq * (1.f / 128.f) - mean * mean;
    float inv = rsqrtf(var + 1e-5f);
    long o = row * 128 + lane * 2;
    if (OUT_BF16) {
        ((short*)out)[o]     = f2bfs((v0 - mean) * inv);
        ((short*)out)[o + 1] = f2bfs((v1 - mean) * inv);
    } else {
        ((float*)out)[o]     = (v0 - mean) * inv;
        ((float*)out)[o + 1] = (v1 - mean) * inv;
    }
}

// ---------------------------------------------------------------------------
// Block-wise attention over prototypes (fused BLN of slots + q scale).
// ---------------------------------------------------------------------------
__global__ __launch_bounds__(256) void bwa_k(float* __restrict__ slots,
                                             const float* __restrict__ mem)
{
    int nb = blockIdx.x, b = blockIdx.y, tid = threadIdx.x;
    __shared__ float qn[8 * 128];
    __shared__ float ml[64 * 129];
    __shared__ float sc[8 * 64];

    for (int idx = tid; idx < 64 * 128; idx += 256) {
        int p = idx >> 7, j = idx & 127;
        ml[p * 129 + j] = mem[(long)(p * 16 + nb) * 128 + j];
    }
    {
        int t = tid >> 5;
        int j0 = (tid & 31) * 4;
        const float* src = slots + (long)(b * 8 + t) * 2048 + nb * 128 + j0;
        float v0 = src[0], v1 = src[1], v2 = src[2], v3 = src[3];
        float s = v0 + v1 + v2 + v3;
        float sq = v0 * v0 + v1 * v1 + v2 * v2 + v3 * v3;
        #pragma unroll
        for (int d = 1; d < 32; d <<= 1) { s += __shfl_xor(s, d); sq += __shfl_xor(sq, d); }
        float mean = s * (1.f / 128.f);
        float var = sq * (1.f / 128.f) - mean * mean;
        float inv = rsqrtf(var + 1e-5f) * 0.08838834764831845f;
        qn[t * 128 + j0]     = (v0 - mean) * inv;
        qn[t * 128 + j0 + 1] = (v1 - mean) * inv;
        qn[t * 128 + j0 + 2] = (v2 - mean) * inv;
        qn[t * 128 + j0 + 3] = (v3 - mean) * inv;
    }
    __syncthreads();
    for (int idx = tid; idx < 512; idx += 256) {
        int t = idx >> 6, p = idx & 63;
        const float* qr = &qn[t * 128];
        const float* mr = &ml[p * 129];
        float acc = 0.f;
        for (int j = 0; j < 128; j++) acc += qr[j] * mr[j];
        sc[t * 64 + p] = acc;
    }
    __syncthreads();
    {
        int w = tid >> 6, lane = tid & 63;
        for (int t = w; t < 8; t += 4) {
            float v = sc[t * 64 + lane];
            float m = v;
            #pragma unroll
            for (int d = 1; d < 64; d <<= 1) m = fmaxf(m, __shfl_xor(m, d));
            float e = expf(v - m);
            float ssum = e;
            #pragma unroll
            for (int d = 1; d < 64; d <<= 1) ssum += __shfl_xor(ssum, d);
            sc[t * 64 + lane] = e / ssum;
        }
    }
    __syncthreads();
    {
        int t = tid >> 5, j0 = (tid & 31) * 4;
        float a0 = 0, a1 = 0, a2 = 0, a3 = 0;
        for (int p = 0; p < 64; p++) {
            float a = sc[t * 64 + p];
            const float* mr = &ml[p * 129 + j0];
            a0 += a * mr[0]; a1 += a * mr[1]; a2 += a * mr[2]; a3 += a * mr[3];
        }
        float* dst = slots + (long)(b * 8 + t) * 2048 + nb * 128 + j0;
        dst[0] = a0; dst[1] = a1; dst[2] = a2; dst[3] = a3;
    }
}

// OUTPUT IS FLOAT32
__global__ __launch_bounds__(256) void out_k(const float* __restrict__ slots,
                                             const float* __restrict__ attn,
                                             float* __restrict__ out)
{
    int idx = blockIdx.x * 256 + threadIdx.x;
    out[idx] = (idx < 524288) ? slots[idx] : attn[idx - 524288];
}

// ===========================================================================
extern "C" void kernel_launch(void* const* d_in, const int* in_sizes, int n_in,
                              void* d_out, int out_size, void* d_ws, size_t ws_size,
                              hipStream_t stream)
{
    (void)in_sizes; (void)n_in; (void)out_size; (void)ws_size;
    const float* inputs = (const float*)d_in[0];
    const float* noise  = (const float*)d_in[1];
    const float* smu    = (const float*)d_in[2];
    const float* sls    = (const float*)d_in[3];
    const float* Wq     = (const float*)d_in[4];
    const float* bq     = (const float*)d_in[5];
    const float* Wk     = (const float*)d_in[6];
    /* d_in[7] = bk: softmax(axis=n)-invariant; dropped */
    const float* Wv     = (const float*)d_in[8];
    const float* bv     = (const float*)d_in[9];
    const float* gWih   = (const float*)d_in[10];
    const float* gWhh   = (const float*)d_in[11];
    const float* gbih   = (const float*)d_in[12];
    const float* gbhh   = (const float*)d_in[13];
    const float* mW1    = (const float*)d_in[14];
    const float* mb1    = (const float*)d_in[15];
    const float* mW2    = (const float*)d_in[16];
    const float* mb2    = (const float*)d_in[17];
    const float* cvec   = (const float*)d_in[18];
    const float* cW1    = (const float*)d_in[19];
    const float* cb1    = (const float*)d_in[20];
    const float* cW2    = (const float*)d_in[21];
    const float* cb2    = (const float*)d_in[22];
    const float* cW3    = (const float*)d_in[23];
    const float* cb3    = (const float*)d_in[24];
    const float* cW4    = (const float*)d_in[25];
    const float* cb4    = (const float*)d_in[26];
    const float* nig    = (const float*)d_in[27];
    const float* nib    = (const float*)d_in[28];
    const float* nsg    = (const float*)d_in[29];
    const float* nsb    = (const float*)d_in[30];

    char* w = (char*)d_ws;
    auto take = [&](size_t bytes) -> char* {
        char* p = w;
        w += (bytes + 255) & ~(size_t)255;
        return p;
    };

    float* slots   = (float*)take((size_t)524288 * 4);
    short* xbf     = (short*)take((size_t)32768 * 256 * 2);
    short* Wqbf    = (short*)take((size_t)2048 * 2048 * 2);
    short* Wkbf    = (short*)take((size_t)256 * 2048 * 2);
    short* Wvbf    = (short*)take((size_t)256 * 2048 * 2);
    short* gWihbf  = (short*)take((size_t)16 * 384 * 128 * 2);
    short* gWhhbf  = (short*)take((size_t)16 * 384 * 128 * 2);
    short* cvecbf  = (short*)take((size_t)1024 * 128 * 2);
    float* M1f     = (float*)take((size_t)256 * 2048 * 4);   // M1T[i,e] f32
    short* WvGTbf  = (short*)take((size_t)16 * 384 * 256 * 2);
    float* b1g     = (float*)take((size_t)6144 * 4);
    float* c1      = (float*)take((size_t)256 * 4);
    short* mW1T    = (short*)take((size_t)16 * 128 * 128 * 2);
    short* mW2T    = (short*)take((size_t)16 * 128 * 128 * 2);
    short* cW1T    = (short*)take((size_t)512 * 128 * 2);
    short* cW2T    = (short*)take((size_t)512 * 512 * 2);
    short* cW3T    = (short*)take((size_t)512 * 512 * 2);
    short* cW4T    = (short*)take((size_t)128 * 512 * 2);
    short* hA      = (short*)take((size_t)1024 * 512 * 2);
    short* hB      = (short*)take((size_t)1024 * 512 * 2);
    float* h4      = (float*)take((size_t)1024 * 128 * 4);
    float* memf    = (float*)take((size_t)1024 * 128 * 4);
    short* s_ln    = (short*)take((size_t)256 * 2048 * 2);
    short* slotsbf = (short*)take((size_t)256 * 2048 * 2);
    float* kqf     = (float*)take((size_t)256 * 256 * 4);
    float* dots    = (float*)take((size_t)32 * 1024 * 8 * 4);
    float* attn    = (float*)take((size_t)32 * 1024 * 8 * 4);
    float* up      = (float*)take((size_t)256 * 256 * 4);
    float* gi      = (float*)take((size_t)256 * 6144 * 4);
    float* gh      = (float*)take((size_t)256 * 6144 * 4);
    short* t1      = (short*)take((size_t)256 * 2048 * 2);
    short* t2      = (short*)take((size_t)256 * 2048 * 2);

    // --- prep: converts, transposes, folded weights ------------------------
    cvt_all_k<<<27136, 256, 0, stream>>>(Wq, Wk, Wv, gWih, gWhh, cvec,
                                         Wqbf, Wkbf, Wvbf, gWihbf, gWhhbf, cvecbf);
    transpose_cvt_k<<<dim3(4, 4, 16),  256, 0, stream>>>(mW1, mW1T, 128, 128, 16384, 16384);
    transpose_cvt_k<<<dim3(4, 4, 16),  256, 0, stream>>>(mW2, mW2T, 128, 128, 16384, 16384);
    transpose_cvt_k<<<dim3(16, 4, 1),  256, 0, stream>>>(cW1, cW1T, 128, 512, 0, 0);
    transpose_cvt_k<<<dim3(16, 16, 1), 256, 0, stream>>>(cW2, cW2T, 512, 512, 0, 0);
    transpose_cvt_k<<<dim3(16, 16, 1), 256, 0, stream>>>(cW3, cW3T, 512, 512, 0, 0);
    transpose_cvt_k<<<dim3(4, 16, 1),  256, 0, stream>>>(cW4, cW4T, 512, 128, 0, 0);
    zero_k<<<2048, 256, 0, stream>>>(M1f, 524288);
    // M1T[i,e] = sum_d Wk[i,d] Wq[e,d]  (split-K=4, f32 atomic)
    gemm_bt<3,0,0,0,0,4><<<dim3(4, 32, 4), 256, 0, stream>>>(
        Wkbf, 2048, 0, Wqbf, 2048, 0, M1f, 2048, 0, nullptr, 0, 256, 2048, 2048, 1.f);
    // WvGT[nb][g,i] = sum_j gWih[nb,g,j] Wv[i, nb*128+j]
    gemm_bt<1,0,0,0,0,1><<<dim3(6, 4, 16), 256, 0, stream>>>(
        gWihbf, 128, 49152, Wvbf, 2048, 128, WvGTbf, 256, 98304, nullptr, 0, 384, 256, 128, 1.f);
    b1g_k<<<24, 256, 0, stream>>>(bv, gWih, b1g);
    c1_k<<<256, 256, 0, stream>>>(bq, Wk, c1);

    init_slots_k<<<2048, 256, 0, stream>>>(noise, smu, sls, slots);
    ln_in_k<<<8192, 256, 0, stream>>>(inputs, nig, nib, xbf);

    // --- concept memory (iteration-invariant) ------------------------------
    gemm_bt<1,1,1,0,0,1><<<dim3(16, 8, 1), 256, 0, stream>>>(cvecbf, 128, 0, cW1T, 128, 0, hA, 512, 0, cb1, 0, 1024, 512, 128, 1.f);
    gemm_bt<1,1,1,0,0,1><<<dim3(16, 8, 1), 256, 0, stream>>>(hA, 512, 0, cW2T, 512, 0, hB, 512, 0, cb2, 0, 1024, 512, 512, 1.f);
    gemm_bt<1,1,1,0,0,1><<<dim3(16, 8, 1), 256, 0, stream>>>(hB, 512, 0, cW3T, 512, 0, hA, 512, 0, cb3, 0, 1024, 512, 512, 1.f);
    gemm_bt<0,0,1,0,0,1><<<dim3(16, 2, 1), 256, 0, stream>>>(hA, 512, 0, cW4T, 512, 0, h4, 128, 0, cb4, 0, 1024, 128, 512, 1.f);
    bln_k<0><<<1024, 64, 0, stream>>>(h4, memf);

    for (int it = 0; it < 3; ++it) {
        ln_slots_k<<<256, 256, 0, stream>>>(slots, nsg, nsb, s_ln, slotsbf, kqf);
        // kq[bs,i] = s_ln @ M1T^T + c1   (split-K=8, f32 atomic)
        gemm_bt<3,0,1,0,1,8><<<dim3(4, 4, 8), 256, 0, stream>>>(
            s_ln, 2048, 0, M1f, 2048, 0, kqf, 256, 0, c1, 0, 256, 256, 2048, 1.f);
        // dots[b,n,s] = scale * x[b] @ kq[b]^T
        gemm_bt<0,0,0,0,1,1><<<dim3(16, 1, 32), 256, 0, stream>>>(
            xbf, 256, 262144, kqf, 256, 2048, dots, 8, 8192, nullptr, 0, 1024, 8, 256, 0.022097086912079608f);
        softmax_k<<<dim3(8, 32), 64, 0, stream>>>(dots, attn, up);
        uprime_k<<<dim3(8, 32), 256, 0, stream>>>(attn, xbf, up);
        // gi = u' @ WvGT + b1g   (Wv folded into gWih; bv folded into b1g)
        gemm_bt<0,0,1,1,0,1><<<dim3(4, 6, 16), 256, 0, stream>>>(
            up, 256, 0, WvGTbf, 256, 98304, gi, 6144, 384, b1g, 384, 256, 384, 256, 1.f);
        gemm_bt<0,0,0,0,0,1><<<dim3(4, 6, 16), 256, 0, stream>>>(
            slotsbf, 2048, 128, gWhhbf, 128, 49152, gh, 6144, 384, nullptr, 0, 256, 384, 128, 1.f);
        gru_k<<<2048, 256, 0, stream>>>(gi, gh, gbih, gbhh, slots);
        // residual block-MLP
        bln_k<1><<<4096, 64, 0, stream>>>(slots, t1);
        gemm_bt<1,1,1,0,0,1><<<dim3(4, 2, 16), 256, 0, stream>>>(t1, 2048, 128, mW1T, 128, 16384, t2, 2048, 128, mb1, 128, 256, 128, 128, 1.f);
        gemm_bt<2,0,1,0,0,1><<<dim3(4, 2, 16), 256, 0, stream>>>(t2, 2048, 128, mW2T, 128, 16384, slots, 2048, 128, mb2, 128, 256, 128, 128, 1.f);
        // block-wise attention over prototypes (in-place slot update)
        bwa_k<<<dim3(16, 32), 256, 0, stream>>>(slots, memf);
    }
    out_k<<<3072, 256, 0, stream>>>(slots, attn, (float*)d_out);
}